// Round 5
// baseline (107.723 us; speedup 1.0000x reference)
//
#include <hip/hip_runtime.h>
#include <stdint.h>

// DynamicMaxPool: per-column k-max pooling with order preservation.
// Two-phase: dense select into ws (block-local layout), coalesced transpose.
//
// Round-4 evidence: select was latency-bound (VALUBusy 30%, 16 waves/CU cap
// from 1 wave/column + 1 block/CU). This version: TWO waves per column
// (32 vals/lane) -> 8192 waves = 32/CU, needs 2 blocks/CU: LDS ~70KB and
// VGPR<=64 (launch_bounds(1024,8)). Hist double-buffered by pass parity with
// per-half planes -> 1 barrier/pass; permuted hist slots -> conflict-free scan.

constexpr int T_ROWS = 4096;
constexpr int C_COLS = 256;
constexpr int NBATCH = 16;
constexpr int SBLOCK = 1024;             // 16 waves = 8 cols x 2 halves
constexpr int COLS_PB = 8;
constexpr int CROWS  = 512;              // rows per staged chunk
constexpr int CPAD   = 9;                // 8 cols + 1 pad (odd -> free reads)
constexpr int NCHUNK = 8;
constexpr int EPL    = 32;               // values per lane (2048/64)
constexpr int NGB    = C_COLS / COLS_PB; // 32 col-groups per batch
constexpr int NBLK   = NBATCH * NGB;     // 512 select blocks
constexpr size_t NTOT = (size_t)NBATCH * T_ROWS * C_COLS;

__device__ __forceinline__ int compute_k(const int* lengths, const int* pool_ranges,
                                         const int* p_top_k, const int* p_layer,
                                         const int* p_total, int b, int* pr_out)
{
    int pr = pool_ranges[b];
    pr = pr < 0 ? 0 : (pr > T_ROWS ? T_ROWS : pr);
    const int len   = lengths[b];
    const int top_k = p_top_k[0];
    const int tot   = p_total[0];
    const int num   = tot - p_layer[0];
    int k = (num * len + tot - 1) / tot;   // ceil, positive ints
    if (k < top_k) k = top_k;
    if (k > pr)    k = pr;
    *pr_out = pr;
    return k;
}

// MODE 0: dense per-column slab into ws (K2 transposes). MODE 1: direct
// scattered writes to out + zero-fill (fallback when ws too small).
template<int MODE>
__global__ __launch_bounds__(SBLOCK, 8)
void kmax_select_kernel(const float* __restrict__ x,
                        const int*   __restrict__ lengths,
                        const int*   __restrict__ pool_ranges,
                        const int*   __restrict__ p_top_k,
                        const int*   __restrict__ p_layer,
                        const int*   __restrict__ p_total,
                        float*       __restrict__ out,
                        float*       __restrict__ ws)
{
    __shared__ float    stage[2][CROWS][CPAD];          // 36,864 B
    __shared__ uint32_t hist[2][COLS_PB][2][256];       // 32,768 B (buf,col,half-plane)
    __shared__ uint32_t wtot[COLS_PB];

    const int t    = threadIdx.x;
    const int lane = t & 63;
    const int wid  = t >> 6;
    const int col  = wid >> 1;           // local column 0..7
    const int half = wid & 1;            // row half: rows [half*2048, +2048)
    const int bid  = blockIdx.x;
    // XCD-chunked swizzle: consecutive lin -> same physical XCD (bid%8),
    // so sibling blocks sharing 64B lines co-reside in one L2.
    const int lin  = (bid & 7) * (NBLK / 8) + (bid >> 3);
    const int b    = lin >> 5;
    const int cgrp = lin & 31;
    const int c0   = cgrp * COLS_PB;
    const int c    = c0 + col;

    int pr;
    const int k = compute_k(lengths, pool_ranges, p_top_k, p_layer, p_total, b, &pr);

    // ---- staged load: chunk = 512 rows x 8 cols; thread loads one float4
    //      (2 threads cover a row's 32B strip; sibling block has the other
    //      half of the 64B line, same XCD). Chunks interleaved h0,h1,h0,..
    //      so both halves' waves stream. 2 chunks of loads in flight. ----
    const int rq = t >> 1;               // row within chunk
    const int q  = t & 1;                // which float4 of the 8-col strip
    const float* xb = x + (size_t)b * T_ROWS * C_COLS + (size_t)c0 + (size_t)(q * 4);
    const int seq[NCHUNK] = {0, 4, 1, 5, 2, 6, 3, 7};

    uint32_t u[EPL];
    float4 ld[2];
    ld[0] = *reinterpret_cast<const float4*>(xb + (size_t)(seq[0] * CROWS + rq) * C_COLS);

    #pragma unroll
    for (int s = 0; s < NCHUNK; ++s) {
        const int ci = seq[s];
        if (s + 1 < NCHUNK)
            ld[(s + 1) & 1] = *reinterpret_cast<const float4*>(
                xb + (size_t)(seq[s + 1] * CROWS + rq) * C_COLS);
        const float4 v = ld[s & 1];
        float* srow = &stage[s & 1][rq][0];
        srow[q * 4 + 0] = v.x;
        srow[q * 4 + 1] = v.y;
        srow[q * 4 + 2] = v.z;
        srow[q * 4 + 3] = v.w;
        if (s == 0) {   // zero both hist buffers once (counts start after s=7 bar)
            uint32_t* hf = &hist[0][0][0][0];
            #pragma unroll
            for (int z = 0; z < (2 * COLS_PB * 2 * 256) / SBLOCK; ++z)
                hf[z * SBLOCK + t] = 0u;
        }
        __syncthreads();
        if ((ci >> 2) == half) {         // this chunk belongs to my row-half
            const int mbase = (ci & 3) * 8;
            #pragma unroll
            for (int mm = 0; mm < 8; ++mm) {
                const int m = mbase + mm;
                const uint32_t w = __float_as_uint(stage[s & 1][mm * 64 + lane][col]);
                const uint32_t key = w ^ ((w >> 31) ? 0xFFFFFFFFu : 0x80000000u);
                u[m] = ((half * 2048 + m * 64 + lane) < pr) ? key : 0u;
                asm("" : "+v"(u[m]));    // pin in VGPR (no remat)
            }
        }
    }

    // ---- radix select of k-th largest; both waves of a column count into
    //      their own plane of the pass-parity hist buffer: 1 barrier/pass. --
    uint32_t prefix = 0u, pmask = 0u, rem = (uint32_t)k;
    if (k > 0) {
        #pragma unroll
        for (int pass = 0; pass < 4; ++pass) {
            const int shift = 24 - 8 * pass;
            uint32_t* hp = &hist[pass & 1][col][half][0];
            #pragma unroll
            for (int m = 0; m < EPL; ++m) {
                const uint32_t ui = u[m];
                if ((ui & pmask) == prefix) {
                    const uint32_t g = 255u - ((ui >> shift) & 255u); // descending rank
                    atomicAdd(&hp[(g & 3u) * 64u + (g >> 2)], 1u);
                }
            }
            __syncthreads();
            // scan: lane owns descending ranks 4*lane..4*lane+3 (conflict-free reads)
            uint32_t c4[4], loc[4], ssum = 0;
            #pragma unroll
            for (int qq = 0; qq < 4; ++qq) {
                const uint32_t cnt = hist[pass & 1][col][0][qq * 64 + lane]
                                   + hist[pass & 1][col][1][qq * 64 + lane];
                c4[qq] = cnt; loc[qq] = ssum; ssum += cnt;
            }
            uint32_t incl = ssum;
            #pragma unroll
            for (int off = 1; off < 64; off <<= 1) {
                const uint32_t nb = __shfl_up(incl, (unsigned)off, 64);
                if (lane >= off) incl += nb;
            }
            const uint32_t gexcl = incl - ssum;
            uint32_t sel = 0, nrem = 0;
            bool found = false;
            #pragma unroll
            for (int qq = 0; qq < 4; ++qq) {
                const uint32_t sbb = gexcl + loc[qq];   // #elems in higher bins
                if (sbb < rem && sbb + c4[qq] >= rem) { // unique crossing
                    sel   = 255u - (uint32_t)(lane * 4 + qq);
                    nrem  = rem - sbb;
                    found = true;
                }
            }
            const unsigned long long fm = __ballot(found);
            const int src = __ffsll(fm) - 1;
            sel  = __shfl(sel,  src, 64);
            nrem = __shfl(nrem, src, 64);
            prefix |= sel << shift;
            pmask  |= 0xFFu << shift;
            rem = nrem;
            // zero my plane of the OTHER buffer (used by pass+1): safe — its
            // last readers (pass-1 scans) finished before this pass's barrier.
            if (pass < 3) {
                uint32_t* hz = &hist[(pass + 1) & 1][col][half][0];
                hz[lane] = 0u; hz[lane + 64] = 0u; hz[lane + 128] = 0u; hz[lane + 192] = 0u;
            }
        }

        // ---- cross-wave (gt,eq) base, then ballot-compact (wave-local) ----
        const uint32_t th = prefix, tn = rem;
        uint32_t gcnt = 0, ecnt = 0;
        #pragma unroll
        for (int m = 0; m < EPL; ++m) {
            const bool v = (half * 2048 + m * 64 + lane) < pr;
            gcnt += (v && u[m] >  th) ? 1u : 0u;
            ecnt += (v && u[m] == th) ? 1u : 0u;
        }
        uint32_t pk = (gcnt << 16) | ecnt;     // totals <= 2048 each
        #pragma unroll
        for (int off = 32; off >= 1; off >>= 1) pk += __shfl_xor(pk, off, 64);
        if (half == 0 && lane == 0) wtot[col] = pk;
        __syncthreads();
        const uint32_t base = half ? wtot[col] : 0u;

        uint32_t G = base >> 16, E = base & 0xFFFFu;
        const unsigned long long ltm = (1ull << lane) - 1ull;
        const size_t wsbase  = (size_t)(b * 64 + (c >> 2)) * (size_t)(T_ROWS * 4) + (size_t)(c & 3);
        const size_t outbase = (size_t)b * T_ROWS * C_COLS + (size_t)c;
        #pragma unroll
        for (int m = 0; m < EPL; ++m) {
            const int row = half * 2048 + m * 64 + lane;
            const uint32_t ui = u[m];
            const bool v    = row < pr;
            const bool mygt = v && (ui > th);
            const bool myeq = v && (ui == th);
            const unsigned long long gm = __ballot(mygt);
            const unsigned long long em = __ballot(myeq);
            const uint32_t my_g = G + (uint32_t)__popcll(gm & ltm);
            const uint32_t my_e = E + (uint32_t)__popcll(em & ltm);
            if (mygt || (myeq && my_e < tn)) {
                const uint32_t pos  = my_g + (my_e < tn ? my_e : tn);
                const uint32_t bits = ui ^ ((ui >> 31) ? 0x80000000u : 0xFFFFFFFFu);
                if (MODE == 0)
                    ws[wsbase + (size_t)pos * 4] = __uint_as_float(bits);
                else
                    out[outbase + (size_t)pos * C_COLS] = __uint_as_float(bits);
            }
            G += (uint32_t)__popcll(gm);
            E += (uint32_t)__popcll(em);
        }
    }

    if (MODE == 1) {
        // zero-fill rows [k, T) of this block's 8 columns (fallback path)
        const int cl = t & 7;
        for (int r = k + (t >> 3); r < T_ROWS; r += SBLOCK / 8)
            out[(size_t)b * T_ROWS * C_COLS + (size_t)r * C_COLS + (size_t)(c0 + cl)] = 0.f;
    }

    // ---- Output 1: pool_result_ranges (k per batch), as float32 ----
    if (cgrp == 0 && t == 0)
        out[NTOT + (size_t)b] = (float)k;
}

// K2: transpose ws[b][cg][pos][4] -> out[b][pos][c] (coalesced both sides)
// and zero-fill rows >= k. 64-pos x 256-col tiles through a 64KB LDS tile.
constexpr int TBLOCK = 256;

__global__ __launch_bounds__(TBLOCK)
void kmax_transpose_kernel(const float* __restrict__ ws,
                           const int*   __restrict__ lengths,
                           const int*   __restrict__ pool_ranges,
                           const int*   __restrict__ p_top_k,
                           const int*   __restrict__ p_layer,
                           const int*   __restrict__ p_total,
                           float*       __restrict__ out)
{
    extern __shared__ float4 tile_s[];   // [64 cg][64 pos] xor-swizzled, 64 KB

    const int bid  = blockIdx.x;
    const int b    = bid >> 6;
    const int tile = bid & 63;
    const int pos0 = tile * 64;

    int pr;
    const int k = compute_k(lengths, pool_ranges, p_top_k, p_layer, p_total, b, &pr);

    const int t = threadIdx.x;
    const int w = t >> 6;
    const int l = t & 63;
    const float4 z4 = make_float4(0.f, 0.f, 0.f, 0.f);
    float4* out4 = reinterpret_cast<float4*>(out);

    if (pos0 < k) {
        const float4* ws4 = reinterpret_cast<const float4*>(ws);
        #pragma unroll
        for (int cgi = 0; cgi < 16; ++cgi) {
            const int cg = cgi * 4 + w;
            tile_s[cg * 64 + (l ^ cg)] =
                ws4[(size_t)(b * 64 + cg) * T_ROWS + (size_t)(pos0 + l)];
        }
        __syncthreads();
        #pragma unroll
        for (int it = 0; it < 16; ++it) {
            const int idx = it * TBLOCK + t;
            const int row = idx >> 6;
            const int cq  = idx & 63;
            const int pos = pos0 + row;
            const float4 v = (pos < k) ? tile_s[cq * 64 + (row ^ cq)] : z4;
            out4[((size_t)b * T_ROWS + (size_t)pos) * (C_COLS / 4) + (size_t)cq] = v;
        }
    } else {
        #pragma unroll
        for (int it = 0; it < 16; ++it) {
            const int idx = it * TBLOCK + t;
            const int row = idx >> 6;
            const int cq  = idx & 63;
            out4[((size_t)b * T_ROWS + (size_t)(pos0 + row)) * (C_COLS / 4) +
                 (size_t)cq] = z4;
        }
    }
}

extern "C" void kernel_launch(void* const* d_in, const int* in_sizes, int n_in,
                              void* d_out, int out_size, void* d_ws, size_t ws_size,
                              hipStream_t stream)
{
    const float* x            = (const float*)d_in[0];
    const int*   lengths      = (const int*)d_in[1];
    const int*   pool_ranges  = (const int*)d_in[2];
    const int*   top_k        = (const int*)d_in[3];
    const int*   layer        = (const int*)d_in[4];
    const int*   total_layers = (const int*)d_in[5];
    float*       out          = (float*)d_out;
    float*       ws           = (float*)d_ws;

    const size_t ws_need = (size_t)NBATCH * 64 * T_ROWS * 4 * sizeof(float); // 64 MiB

    if (ws_size >= ws_need) {
        hipLaunchKernelGGL(kmax_select_kernel<0>, dim3(NBLK), dim3(SBLOCK), 0, stream,
                           x, lengths, pool_ranges, top_k, layer, total_layers, out, ws);
        hipLaunchKernelGGL(kmax_transpose_kernel, dim3(NBATCH * 64), dim3(TBLOCK), 65536, stream,
                           ws, lengths, pool_ranges, top_k, layer, total_layers, out);
    } else {
        hipLaunchKernelGGL(kmax_select_kernel<1>, dim3(NBLK), dim3(SBLOCK), 0, stream,
                           x, lengths, pool_ranges, top_k, layer, total_layers, out, ws);
    }
}

// Round 6
// 101.034 us; speedup vs baseline: 1.0662x; 1.0662x over previous
//
#include <hip/hip_runtime.h>
#include <stdint.h>

// DynamicMaxPool: per-column k-max pooling with order preservation.
// x: [B=16, T=4096, C=256] f32. For each (b,c): keep the k largest of the
// first pr rows (ties -> lower row index, stable), compacted to rows 0..k-1
// in original row order; rows k..T-1 zero. k is per-batch.
//
// Round-5 evidence: holding all data in registers caps at 16 waves/CU
// (data = 50% of the register file); pushing occupancy to 8 waves/SIMD made
// the compiler cap VGPR=32 and spill (WRITE 135MB). Round-4's 70us was the
// in-kernel staging machinery (8 barriers, ~128 ds ops/thread, loads not in
// flight). This version splits into 3 kernels:
//  K0: x[b][t][c] -> sortable keys xT[b][c][t]  (clean coalesced transpose)
//  K1: wave-per-column select; contiguous b128 loads straight to registers,
//      zero barriers, wave-private hist; writes dense slab IN-PLACE over xT.
//  K2: slab [b][c][pos] -> out[b][pos][c] transpose + zero-fill.

constexpr int T_ROWS = 4096;
constexpr int C_COLS = 256;
constexpr int NBATCH = 16;
constexpr int NSUB   = 8;                 // hist sub-counters (lane & 7)
constexpr size_t NTOT = (size_t)NBATCH * T_ROWS * C_COLS;

__device__ __forceinline__ int compute_k(const int* lengths, const int* pool_ranges,
                                         const int* p_top_k, const int* p_layer,
                                         const int* p_total, int b, int* pr_out)
{
    int pr = pool_ranges[b];
    pr = pr < 0 ? 0 : (pr > T_ROWS ? T_ROWS : pr);
    const int len   = lengths[b];
    const int top_k = p_top_k[0];
    const int tot   = p_total[0];
    const int num   = tot - p_layer[0];
    int k = (num * len + tot - 1) / tot;   // ceil, positive ints
    if (k < top_k) k = top_k;
    if (k > pr)    k = pr;
    *pr_out = pr;
    return k;
}

// ---- K0: transpose + key transform. grid 4096 (b, 64 t-tiles, 4 c-tiles) ----
__global__ __launch_bounds__(256)
void transpose_key_kernel(const float* __restrict__ x, uint32_t* __restrict__ xT)
{
    __shared__ uint32_t tile[64][65];
    const int bid = blockIdx.x;
    const int b   = bid >> 8;
    const int tt  = (bid >> 2) & 63;
    const int ct  = bid & 3;
    const int t0  = tt * 64, c0 = ct * 64;
    const int tid = threadIdx.x;
    const int qq  = tid & 15;            // quad index within 64
    const int rr  = tid >> 4;            // 0..15

    #pragma unroll
    for (int it = 0; it < 4; ++it) {
        const int r = it * 16 + rr;
        const float4 v = *reinterpret_cast<const float4*>(
            x + ((size_t)(b * T_ROWS + t0 + r) << 8) + c0 + qq * 4);
        const uint32_t w4[4] = {__float_as_uint(v.x), __float_as_uint(v.y),
                                __float_as_uint(v.z), __float_as_uint(v.w)};
        #pragma unroll
        for (int j = 0; j < 4; ++j)
            tile[qq * 4 + j][r] = w4[j] ^ ((w4[j] >> 31) ? 0xFFFFFFFFu : 0x80000000u);
    }
    __syncthreads();
    #pragma unroll
    for (int it = 0; it < 4; ++it) {
        const int cl = it * 16 + rr;
        uint4 o;
        o.x = tile[cl][qq * 4 + 0];
        o.y = tile[cl][qq * 4 + 1];
        o.z = tile[cl][qq * 4 + 2];
        o.w = tile[cl][qq * 4 + 3];
        *reinterpret_cast<uint4*>(
            xT + ((size_t)(b * C_COLS + c0 + cl) << 12) + t0 + qq * 4) = o;
    }
}

// ---- K1: select. grid 1024 blocks x 256 thr (4 waves = 4 columns). ----
__global__ __launch_bounds__(256, 5)
void kmax_select_kernel(const uint32_t* __restrict__ xT,
                        const int* __restrict__ lengths,
                        const int* __restrict__ pool_ranges,
                        const int* __restrict__ p_top_k,
                        const int* __restrict__ p_layer,
                        const int* __restrict__ p_total,
                        float* __restrict__ out,
                        float* __restrict__ ws)
{
    __shared__ uint32_t hist[4][256 * NSUB];   // 32 KB, wave-private slices

    const int t    = threadIdx.x;
    const int lane = t & 63;
    const int wid  = t >> 6;
    const int bid  = blockIdx.x;
    const int b    = bid >> 6;
    const int cg   = bid & 63;
    const int c    = cg * 4 + wid;

    int pr;
    const int k = compute_k(lengths, pool_ranges, p_top_k, p_layer, p_total, b, &pr);

    // contiguous column loads: instr i covers rows [i*256 + lane*4, +4) — a
    // full 1KB line per wave-instr, 16 b128 loads all in flight.
    const uint4* cp = reinterpret_cast<const uint4*>(
                          xT + ((size_t)(b * C_COLS + c) << 12)) + lane;
    uint4 ld[16];
    #pragma unroll
    for (int i = 0; i < 16; ++i) ld[i] = cp[i * 64];

    const int rb = lane * 4;
    uint32_t u[64];                       // u[i*4+j] = row i*256 + lane*4 + j
    #pragma unroll
    for (int i = 0; i < 16; ++i) {
        const int rowb = i * 256 + rb;
        u[i * 4 + 0] = (rowb + 0 < pr) ? ld[i].x : 0u;
        u[i * 4 + 1] = (rowb + 1 < pr) ? ld[i].y : 0u;
        u[i * 4 + 2] = (rowb + 2 < pr) ? ld[i].z : 0u;
        u[i * 4 + 3] = (rowb + 3 < pr) ? ld[i].w : 0u;
        asm("" : "+v"(u[i*4+0]), "+v"(u[i*4+1]), "+v"(u[i*4+2]), "+v"(u[i*4+3]));
    }

    if (k > 0) {
        uint32_t* hp = &hist[wid][0];
        uint32_t prefix = 0u, pmask = 0u, rem = (uint32_t)k;
        const uint32_t sub = lane & (NSUB - 1);

        #pragma unroll 1                  // keep pass loop rolled (I$)
        for (int pass = 0; pass < 4; ++pass) {
            const int shift = 24 - 8 * pass;
            // zero my wave's hist (conflict-free b128 stores)
            uint4* hp4 = reinterpret_cast<uint4*>(hp);
            const uint4 z4 = make_uint4(0u, 0u, 0u, 0u);
            #pragma unroll
            for (int z = 0; z < 8; ++z) hp4[z * 64 + lane] = z4;
            // count (fire-and-forget ds_add; wave-private -> no races)
            #pragma unroll
            for (int m = 0; m < 64; ++m) {
                const uint32_t ui = u[m];
                if ((ui & pmask) == prefix)
                    atomicAdd(&hp[((ui >> shift) & 255u) * NSUB + sub], 1u);
            }
            // descending scan: lane owns desc positions 4*lane..4*lane+3,
            // i.e. bins 255-4*lane-q  -> 32 consecutive words per lane.
            const uint4* rp = reinterpret_cast<const uint4*>(
                                  &hp[(252 - 4 * lane) * NSUB]);
            uint32_t cnt[4];
            #pragma unroll
            for (int bb = 0; bb < 4; ++bb) {
                const uint4 a = rp[bb * 2 + 0];
                const uint4 d = rp[bb * 2 + 1];
                cnt[bb] = a.x + a.y + a.z + a.w + d.x + d.y + d.z + d.w;
            }
            uint32_t c4[4], loc[4], s = 0;
            #pragma unroll
            for (int q = 0; q < 4; ++q) { c4[q] = cnt[3 - q]; loc[q] = s; s += c4[q]; }
            uint32_t incl = s;
            #pragma unroll
            for (int off = 1; off < 64; off <<= 1) {
                const uint32_t nb = __shfl_up(incl, (unsigned)off, 64);
                if (lane >= off) incl += nb;
            }
            const uint32_t gexcl = incl - s;
            uint32_t sel = 0, nrem = 0;
            bool found = false;
            #pragma unroll
            for (int q = 0; q < 4; ++q) {
                const uint32_t sbb = gexcl + loc[q];    // elems in higher bins
                if (sbb < rem && sbb + c4[q] >= rem) {  // unique crossing
                    sel   = 255u - (uint32_t)(4 * lane + q);
                    nrem  = rem - sbb;
                    found = true;
                }
            }
            const unsigned long long fm = __ballot(found);
            const int src = __ffsll(fm) - 1;
            sel  = __shfl(sel,  src, 64);
            nrem = __shfl(nrem, src, 64);
            prefix |= sel << shift;
            pmask  |= 0xFFu << shift;
            rem = nrem;
        }

        // ---- keep + compact; write dense slab IN-PLACE over this column
        //      (all reads already in registers -> safe). ----
        const uint32_t th = prefix, tn = rem;
        uint32_t G = 0, E = 0;
        float* dst = ws + ((size_t)(b * C_COLS + c) << 12);
        #pragma unroll
        for (int i = 0; i < 16; ++i) {
            const int rowb = i * 256 + rb;
            uint32_t gt[4], eq[4], pk = 0;
            #pragma unroll
            for (int j = 0; j < 4; ++j) {
                const uint32_t ui = u[i * 4 + j];
                gt[j] = (ui > th) ? 1u : 0u;
                eq[j] = ((rowb + j < pr) && ui == th) ? 1u : 0u;
                pk += (gt[j] << 16) | eq[j];
            }
            uint32_t incl = pk;
            #pragma unroll
            for (int off = 1; off < 64; off <<= 1) {
                const uint32_t nb = __shfl_up(incl, (unsigned)off, 64);
                if (lane >= off) incl += nb;
            }
            const uint32_t tot  = __shfl(incl, 63, 64);
            const uint32_t base = incl - pk;
            uint32_t g = G + (base >> 16), e = E + (base & 0xFFFFu);
            #pragma unroll
            for (int j = 0; j < 4; ++j) {
                if (gt[j] || (eq[j] && e < tn)) {
                    const uint32_t pos  = g + (e < tn ? e : tn);
                    const uint32_t ui   = u[i * 4 + j];
                    const uint32_t bits = ui ^ ((ui >> 31) ? 0x80000000u : 0xFFFFFFFFu);
                    dst[pos] = __uint_as_float(bits);
                }
                g += gt[j];
                e += eq[j];
            }
            G += tot >> 16;
            E += tot & 0xFFFFu;
        }
    }

    // Output 1: pool_result_ranges (k per batch), as float32
    if (cg == 0 && t == 0)
        out[NTOT + (size_t)b] = (float)k;
}

// ---- K2: slab [b][c][pos] -> out[b][pos][c] + zero-fill. grid 4096. ----
__global__ __launch_bounds__(256)
void finalize_kernel(const float* __restrict__ ws,
                     const int* __restrict__ lengths,
                     const int* __restrict__ pool_ranges,
                     const int* __restrict__ p_top_k,
                     const int* __restrict__ p_layer,
                     const int* __restrict__ p_total,
                     float* __restrict__ out)
{
    __shared__ float tile[64][65];
    const int bid  = blockIdx.x;
    const int b    = bid >> 8;
    const int pt   = (bid >> 2) & 63;
    const int ct   = bid & 3;
    const int pos0 = pt * 64, c0 = ct * 64;

    int pr;
    const int k = compute_k(lengths, pool_ranges, p_top_k, p_layer, p_total, b, &pr);

    const int tid = threadIdx.x;
    const int qq  = tid & 15;
    const int rr  = tid >> 4;
    float4* out4 = reinterpret_cast<float4*>(out);
    const float4 z4 = make_float4(0.f, 0.f, 0.f, 0.f);

    if (pos0 < k) {
        const float4* ws4 = reinterpret_cast<const float4*>(ws);
        #pragma unroll
        for (int it = 0; it < 4; ++it) {
            const int cl = it * 16 + rr;
            const float4 v = ws4[((size_t)(b * C_COLS + c0 + cl) << 10)
                                 + (pos0 >> 2) + qq];
            tile[cl][qq * 4 + 0] = v.x;
            tile[cl][qq * 4 + 1] = v.y;
            tile[cl][qq * 4 + 2] = v.z;
            tile[cl][qq * 4 + 3] = v.w;
        }
        __syncthreads();
        #pragma unroll
        for (int it = 0; it < 4; ++it) {
            const int r = it * 16 + rr;
            float4 v;
            v.x = tile[qq * 4 + 0][r];
            v.y = tile[qq * 4 + 1][r];
            v.z = tile[qq * 4 + 2][r];
            v.w = tile[qq * 4 + 3][r];
            if (pos0 + r >= k) v = z4;        // straddling tile: zero past k
            out4[((size_t)(b * T_ROWS + pos0 + r) << 6) + (c0 >> 2) + qq] = v;
        }
    } else {
        #pragma unroll
        for (int it = 0; it < 4; ++it) {
            const int r = it * 16 + rr;
            out4[((size_t)(b * T_ROWS + pos0 + r) << 6) + (c0 >> 2) + qq] = z4;
        }
    }
}

extern "C" void kernel_launch(void* const* d_in, const int* in_sizes, int n_in,
                              void* d_out, int out_size, void* d_ws, size_t ws_size,
                              hipStream_t stream)
{
    const float* x            = (const float*)d_in[0];
    const int*   lengths      = (const int*)d_in[1];
    const int*   pool_ranges  = (const int*)d_in[2];
    const int*   top_k        = (const int*)d_in[3];
    const int*   layer        = (const int*)d_in[4];
    const int*   total_layers = (const int*)d_in[5];
    float*       out          = (float*)d_out;
    float*       ws           = (float*)d_ws;   // 64 MiB: xT keys, then slab (in-place)

    hipLaunchKernelGGL(transpose_key_kernel, dim3(4096), dim3(256), 0, stream,
                       x, (uint32_t*)ws);
    hipLaunchKernelGGL(kmax_select_kernel, dim3(1024), dim3(256), 0, stream,
                       (const uint32_t*)ws, lengths, pool_ranges,
                       top_k, layer, total_layers, out, ws);
    hipLaunchKernelGGL(finalize_kernel, dim3(4096), dim3(256), 0, stream,
                       ws, lengths, pool_ranges, top_k, layer, total_layers, out);
}

// Round 7
// 90.702 us; speedup vs baseline: 1.1877x; 1.1139x over previous
//
#include <hip/hip_runtime.h>
#include <stdint.h>

// DynamicMaxPool: per-column k-max pooling with order preservation.
// x: [B=16, T=4096, C=256] f32. For each (b,c): keep the k largest of the
// first pr rows (ties -> lower row index, stable), compacted to rows 0..k-1
// in original row order; rows k..T-1 zero. k is per-batch.
//
//  K0: x[b][t][c] -> sortable keys xT[b][c][t]  (coalesced transpose)
//  K1: wave-per-column radix select; pipelined b128 loads (depth 4, fused
//      mask -> peak ~95 regs under a 128-reg budget: launch_bounds(256,4) —
//      rounds 5/6 lost to pressure-edge spills), conflict-free hist scan
//      (hist[sub][255-bin]: lane-stride-16B b128 reads), zero barriers,
//      dense slab written in-place over xT.
//  K2: slab [b][c][pos] -> out[b][pos][c] transpose + zero-fill.

constexpr int T_ROWS = 4096;
constexpr int C_COLS = 256;
constexpr int NBATCH = 16;
constexpr int NSUB   = 8;                 // hist sub-planes (lane & 7)
constexpr size_t NTOT = (size_t)NBATCH * T_ROWS * C_COLS;

__device__ __forceinline__ int compute_k(const int* lengths, const int* pool_ranges,
                                         const int* p_top_k, const int* p_layer,
                                         const int* p_total, int b, int* pr_out)
{
    int pr = pool_ranges[b];
    pr = pr < 0 ? 0 : (pr > T_ROWS ? T_ROWS : pr);
    const int len   = lengths[b];
    const int top_k = p_top_k[0];
    const int tot   = p_total[0];
    const int num   = tot - p_layer[0];
    int k = (num * len + tot - 1) / tot;   // ceil, positive ints
    if (k < top_k) k = top_k;
    if (k > pr)    k = pr;
    *pr_out = pr;
    return k;
}

// ---- K0: transpose + key transform. grid 4096 (b, 64 t-tiles, 4 c-tiles) ----
__global__ __launch_bounds__(256)
void transpose_key_kernel(const float* __restrict__ x, uint32_t* __restrict__ xT)
{
    __shared__ uint32_t tile[64][65];
    const int bid = blockIdx.x;
    const int b   = bid >> 8;
    const int tt  = (bid >> 2) & 63;
    const int ct  = bid & 3;
    const int t0  = tt * 64, c0 = ct * 64;
    const int tid = threadIdx.x;
    const int qq  = tid & 15;            // quad index within 64
    const int rr  = tid >> 4;            // 0..15

    #pragma unroll
    for (int it = 0; it < 4; ++it) {
        const int r = it * 16 + rr;
        const float4 v = *reinterpret_cast<const float4*>(
            x + ((size_t)(b * T_ROWS + t0 + r) << 8) + c0 + qq * 4);
        const uint32_t w4[4] = {__float_as_uint(v.x), __float_as_uint(v.y),
                                __float_as_uint(v.z), __float_as_uint(v.w)};
        #pragma unroll
        for (int j = 0; j < 4; ++j)
            tile[qq * 4 + j][r] = w4[j] ^ ((w4[j] >> 31) ? 0xFFFFFFFFu : 0x80000000u);
    }
    __syncthreads();
    #pragma unroll
    for (int it = 0; it < 4; ++it) {
        const int cl = it * 16 + rr;
        uint4 o;
        o.x = tile[cl][qq * 4 + 0];
        o.y = tile[cl][qq * 4 + 1];
        o.z = tile[cl][qq * 4 + 2];
        o.w = tile[cl][qq * 4 + 3];
        *reinterpret_cast<uint4*>(
            xT + ((size_t)(b * C_COLS + c0 + cl) << 12) + t0 + qq * 4) = o;
    }
}

// ---- K1: select. grid 1024 blocks x 256 thr (4 waves = 4 columns). ----
__global__ __launch_bounds__(256, 4)
void kmax_select_kernel(const uint32_t* __restrict__ xT,
                        const int* __restrict__ lengths,
                        const int* __restrict__ pool_ranges,
                        const int* __restrict__ p_top_k,
                        const int* __restrict__ p_layer,
                        const int* __restrict__ p_total,
                        float* __restrict__ out,
                        float* __restrict__ ws)
{
    __shared__ uint32_t hist[4][NSUB][256];    // 32 KB, wave-private [wid]

    const int t    = threadIdx.x;
    const int lane = t & 63;
    const int wid  = t >> 6;
    const int bid  = blockIdx.x;
    const int b    = bid >> 6;
    const int cg   = bid & 63;
    const int c    = cg * 4 + wid;

    int pr;
    const int k = compute_k(lengths, pool_ranges, p_top_k, p_layer, p_total, b, &pr);

    // contiguous column loads (1KB line per wave-instr), depth-4 pipeline
    // fused with mask/convert so peak live regs stay ~95 (< 128 budget).
    const uint4* cp = reinterpret_cast<const uint4*>(
                          xT + ((size_t)(b * C_COLS + c) << 12)) + lane;
    const int rb = lane * 4;
    uint32_t u[64];                       // u[i*4+j] = row i*256 + lane*4 + j
    uint4 pf[4];
    #pragma unroll
    for (int i = 0; i < 4; ++i) pf[i] = cp[i * 64];
    #pragma unroll
    for (int i = 0; i < 16; ++i) {
        const uint4 v = pf[i & 3];
        if (i + 4 < 16) pf[i & 3] = cp[(i + 4) * 64];
        const int rowb = i * 256 + rb;
        u[i * 4 + 0] = (rowb + 0 < pr) ? v.x : 0u;
        u[i * 4 + 1] = (rowb + 1 < pr) ? v.y : 0u;
        u[i * 4 + 2] = (rowb + 2 < pr) ? v.z : 0u;
        u[i * 4 + 3] = (rowb + 3 < pr) ? v.w : 0u;
        asm("" : "+v"(u[i*4+0]), "+v"(u[i*4+1]), "+v"(u[i*4+2]), "+v"(u[i*4+3]));
    }

    if (k > 0) {
        uint32_t* hp = &hist[wid][0][0];
        uint32_t prefix = 0u, pmask = 0u, rem = (uint32_t)k;
        const uint32_t sub = lane & (NSUB - 1);

        #pragma unroll 1                  // keep pass loop rolled (I$)
        for (int pass = 0; pass < 4; ++pass) {
            const int shift = 24 - 8 * pass;
            // zero my wave's hist: contiguous b128, conflict-free
            uint4* hp4 = reinterpret_cast<uint4*>(hp);
            const uint4 z4 = make_uint4(0u, 0u, 0u, 0u);
            #pragma unroll
            for (int z = 0; z < 8; ++z) hp4[z * 64 + lane] = z4;
            // count at hist[sub][255-bin] (descending index inside plane)
            #pragma unroll
            for (int m = 0; m < 64; ++m) {
                const uint32_t ui = u[m];
                if ((ui & pmask) == prefix)
                    atomicAdd(&hp[sub * 256 + (255u - ((ui >> shift) & 255u))], 1u);
            }
            // scan: lane owns descending positions d = 4*lane..4*lane+3.
            // Read hp[s*256 + 4*lane .. +3]: lane-stride 16B -> conflict-free.
            uint32_t c4[4] = {0u, 0u, 0u, 0u};
            #pragma unroll
            for (int s = 0; s < NSUB; ++s) {
                const uint4 a = *reinterpret_cast<const uint4*>(&hp[s * 256 + 4 * lane]);
                c4[0] += a.x; c4[1] += a.y; c4[2] += a.z; c4[3] += a.w;
            }
            uint32_t loc[4], ssum = 0;
            #pragma unroll
            for (int q = 0; q < 4; ++q) { loc[q] = ssum; ssum += c4[q]; }
            uint32_t incl = ssum;
            #pragma unroll
            for (int off = 1; off < 64; off <<= 1) {
                const uint32_t nb = __shfl_up(incl, (unsigned)off, 64);
                if (lane >= off) incl += nb;
            }
            const uint32_t gexcl = incl - ssum;
            uint32_t sel = 0, nrem = 0;
            bool found = false;
            #pragma unroll
            for (int q = 0; q < 4; ++q) {
                const uint32_t sbb = gexcl + loc[q];    // elems in higher bins
                if (sbb < rem && sbb + c4[q] >= rem) {  // unique crossing
                    sel   = 255u - (uint32_t)(4 * lane + q);
                    nrem  = rem - sbb;
                    found = true;
                }
            }
            const unsigned long long fm = __ballot(found);
            const int src = __ffsll(fm) - 1;
            sel  = __shfl(sel,  src, 64);
            nrem = __shfl(nrem, src, 64);
            prefix |= sel << shift;
            pmask  |= 0xFFu << shift;
            rem = nrem;
        }

        // ---- keep + compact; write dense slab IN-PLACE over this column
        //      (all reads already in registers -> safe). ----
        const uint32_t th = prefix, tn = rem;
        uint32_t G = 0, E = 0;
        float* dst = ws + ((size_t)(b * C_COLS + c) << 12);
        #pragma unroll
        for (int i = 0; i < 16; ++i) {
            const int rowb = i * 256 + rb;
            uint32_t gt[4], eq[4], pk = 0;
            #pragma unroll
            for (int j = 0; j < 4; ++j) {
                const uint32_t ui = u[i * 4 + j];
                gt[j] = (ui > th) ? 1u : 0u;
                eq[j] = ((rowb + j < pr) && ui == th) ? 1u : 0u;
                pk += (gt[j] << 16) | eq[j];
            }
            uint32_t incl = pk;
            #pragma unroll
            for (int off = 1; off < 64; off <<= 1) {
                const uint32_t nb = __shfl_up(incl, (unsigned)off, 64);
                if (lane >= off) incl += nb;
            }
            const uint32_t tot  = __shfl(incl, 63, 64);
            const uint32_t base = incl - pk;
            uint32_t g = G + (base >> 16), e = E + (base & 0xFFFFu);
            #pragma unroll
            for (int j = 0; j < 4; ++j) {
                if (gt[j] || (eq[j] && e < tn)) {
                    const uint32_t pos  = g + (e < tn ? e : tn);
                    const uint32_t ui   = u[i * 4 + j];
                    const uint32_t bits = ui ^ ((ui >> 31) ? 0x80000000u : 0xFFFFFFFFu);
                    dst[pos] = __uint_as_float(bits);
                }
                g += gt[j];
                e += eq[j];
            }
            G += tot >> 16;
            E += tot & 0xFFFFu;
        }
    }

    // Output 1: pool_result_ranges (k per batch), as float32
    if (cg == 0 && t == 0)
        out[NTOT + (size_t)b] = (float)k;
}

// ---- K2: slab [b][c][pos] -> out[b][pos][c] + zero-fill. grid 4096. ----
__global__ __launch_bounds__(256)
void finalize_kernel(const float* __restrict__ ws,
                     const int* __restrict__ lengths,
                     const int* __restrict__ pool_ranges,
                     const int* __restrict__ p_top_k,
                     const int* __restrict__ p_layer,
                     const int* __restrict__ p_total,
                     float* __restrict__ out)
{
    __shared__ float tile[64][65];
    const int bid  = blockIdx.x;
    const int b    = bid >> 8;
    const int pt   = (bid >> 2) & 63;
    const int ct   = bid & 3;
    const int pos0 = pt * 64, c0 = ct * 64;

    int pr;
    const int k = compute_k(lengths, pool_ranges, p_top_k, p_layer, p_total, b, &pr);

    const int tid = threadIdx.x;
    const int qq  = tid & 15;
    const int rr  = tid >> 4;
    float4* out4 = reinterpret_cast<float4*>(out);
    const float4 z4 = make_float4(0.f, 0.f, 0.f, 0.f);

    if (pos0 < k) {
        const float4* ws4 = reinterpret_cast<const float4*>(ws);
        #pragma unroll
        for (int it = 0; it < 4; ++it) {
            const int cl = it * 16 + rr;
            const float4 v = ws4[((size_t)(b * C_COLS + c0 + cl) << 10)
                                 + (pos0 >> 2) + qq];
            tile[cl][qq * 4 + 0] = v.x;
            tile[cl][qq * 4 + 1] = v.y;
            tile[cl][qq * 4 + 2] = v.z;
            tile[cl][qq * 4 + 3] = v.w;
        }
        __syncthreads();
        #pragma unroll
        for (int it = 0; it < 4; ++it) {
            const int r = it * 16 + rr;
            float4 v;
            v.x = tile[qq * 4 + 0][r];
            v.y = tile[qq * 4 + 1][r];
            v.z = tile[qq * 4 + 2][r];
            v.w = tile[qq * 4 + 3][r];
            if (pos0 + r >= k) v = z4;        // straddling tile: zero past k
            out4[((size_t)(b * T_ROWS + pos0 + r) << 6) + (c0 >> 2) + qq] = v;
        }
    } else {
        #pragma unroll
        for (int it = 0; it < 4; ++it) {
            const int r = it * 16 + rr;
            out4[((size_t)(b * T_ROWS + pos0 + r) << 6) + (c0 >> 2) + qq] = z4;
        }
    }
}

extern "C" void kernel_launch(void* const* d_in, const int* in_sizes, int n_in,
                              void* d_out, int out_size, void* d_ws, size_t ws_size,
                              hipStream_t stream)
{
    const float* x            = (const float*)d_in[0];
    const int*   lengths      = (const int*)d_in[1];
    const int*   pool_ranges  = (const int*)d_in[2];
    const int*   top_k        = (const int*)d_in[3];
    const int*   layer        = (const int*)d_in[4];
    const int*   total_layers = (const int*)d_in[5];
    float*       out          = (float*)d_out;
    float*       ws           = (float*)d_ws;   // 64 MiB: xT keys, then slab (in-place)

    hipLaunchKernelGGL(transpose_key_kernel, dim3(4096), dim3(256), 0, stream,
                       x, (uint32_t*)ws);
    hipLaunchKernelGGL(kmax_select_kernel, dim3(1024), dim3(256), 0, stream,
                       (const uint32_t*)ws, lengths, pool_ranges,
                       top_k, layer, total_layers, out, ws);
    hipLaunchKernelGGL(finalize_kernel, dim3(4096), dim3(256), 0, stream,
                       ws, lengths, pool_ranges, top_k, layer, total_layers, out);
}